// Round 9
// baseline (4729.083 us; speedup 1.0000x reference)
//
#include <hip/hip_runtime.h>
#include <math.h>

// ---------------------------------------------------------------------------
// FNO-GRU 2D: B=16, SX=SY=64, W=64 channels, T=20 steps, YH=33, NFREQ=2112.
// Weights stay in natural [i][o][f] layout (f fastest).
// Workspace (~69 MB):
//   h  : [b][c][x][y] float, 4,194,304
//   B0/B1/B2 : spectral float2 buffers, 2,162,688 each, image-major [img][f].
// Dispatches/step: pw2, fifft_r, pw1, fifft_n, yproj.
//
// LADDER: 195 (direct) -> 118 (gld_lds NBUF=2) -> 7361 REGRESS (manual
// vmcnt r3 -- DO NOT reintroduce) -> 110 (1b/wave) -> 109 (KI=4) ->
// 93 (T14 reg-staging r6) -> 92 + fifft fixes land (r8, total 4226).
// Round-8 POST-MORTEM: distance-2 prefetch NEUTRAL -> load->write distance
// was not the limiter. Recount: LDS pipe ~37%, VALU 45%, HBM ~30% -- nothing
// saturated. Binding constraint = grid: 1056 blocks = 4.125/CU, occupancy
// 22% (~7 waves/CU) -> latency holes uncovered, HBM stuck at ~2 TB/s.
// Round-13 (this round): re-partition pw kernels to 128-thread blocks
// (2 waves, 4 b per block), grid (66,8,4) = 2112 blocks = 8.25/CU; LDS
// 20/12 KB -> 8 blocks/CU co-resident. Per-thread compute map, 32-float
// accumulators, loop/sync structure, distance-2 reg staging UNCHANGED;
// only the wave->(array,ki) staging assignment is re-derived:
//   pw2: wave w stages weight arrays 2w,2w+1 (both ki) + Hf ki=w (5 loads)
//   pw1: wave w stages whr+whi at ki=w + Hf ki=w (3 loads)
// ---------------------------------------------------------------------------

#define NIMG   1024         // B*W images
#define NFREQ  2112         // 64*33
#define IMGSZ  4096         // 64*64
#define INV_N  (1.0f/4096.0f)

constexpr int brev6(int i) {
    int r = 0;
    for (int b = 0; b < 6; ++b) r |= ((i >> b) & 1) << (5 - b);
    return r;
}

// 64-point complex FFT, fully unrolled radix-2 DIT. DSIGN=-1 fwd, +1 inv.
template <int DSIGN>
__device__ __forceinline__ void fft64(float* xr, float* xi,
                                      const float* cs, const float* sn) {
#pragma unroll
    for (int i = 0; i < 64; ++i) {
        const int j = brev6(i);
        if (j > i) {
            float tr = xr[i]; xr[i] = xr[j]; xr[j] = tr;
            float ti = xi[i]; xi[i] = xi[j]; xi[j] = ti;
        }
    }
#pragma unroll
    for (int s = 1; s <= 6; ++s) {
        const int m = 1 << s, h = m >> 1, step = 64 >> s;
#pragma unroll
        for (int j = 0; j < h; ++j) {
            const int tw = j * step;
            float c = 1.0f, sg = 0.0f;
            if (tw != 0) {
                c  = cs[tw];
                sg = (DSIGN < 0) ? -sn[tw] : sn[tw];
            }
#pragma unroll
            for (int k = j; k < 64; k += m) {
                const int p = k, q = k + h;
                const float vr = xr[q], vi = xi[q];
                float tr, ti;
                if (tw == 0) { tr = vr; ti = vi; }
                else         { tr = c * vr - sg * vi; ti = c * vi + sg * vr; }
                const float ur = xr[p], ui = xi[p];
                xr[p] = ur + tr; xi[p] = ui + ti;
                xr[q] = ur - tr; xi[q] = ui - ti;
            }
        }
    }
}

__device__ __forceinline__ void init_twiddles(float* cs, float* sn, int t) {
    float s, c;
    sincosf(6.28318530717958647692f * (float)t * (1.0f / 64.0f), &s, &c);
    cs[t] = c; sn[t] = s;
}

__device__ __forceinline__ float sigmoidf_(float v) {
    return 1.0f / (1.0f + expf(-v));
}

// ---- shared FFT pass helpers (lds: float2[64*33], row-major [x][k]) -------
// lds must be 16B-aligned (declared as float4[1056] in kernels).

// coalesced image copy helpers (64 threads, 1056 float4s)
__device__ __forceinline__ void copy_g2l(float4* dst, const float4* src, int t) {
#pragma unroll
    for (int j = 0; j < 16; ++j) dst[j * 64 + t] = src[j * 64 + t];
    if (t < 32) dst[1024 + t] = src[1024 + t];
}
__device__ __forceinline__ void copy_l2g(float4* dst, const float4* src, int t) {
#pragma unroll
    for (int j = 0; j < 16; ++j) dst[j * 64 + t] = src[j * 64 + t];
    if (t < 32) dst[1024 + t] = src[1024 + t];
}

// inverse fft along x: stage F into lds (coalesced), then column FFTs
// in-place (lockstep read-then-write within the single wave).
__device__ __forceinline__ void ifft_pass_x(const float2* __restrict__ F,
                                            float2* lds, const float* cs,
                                            const float* sn, int t) {
    __syncthreads();
    copy_g2l((float4*)lds, (const float4*)F, t);
    __syncthreads();
    if (t < 33) {
        float ar[64], ai[64];
#pragma unroll
        for (int kx = 0; kx < 64; ++kx) {
            float2 v = lds[kx * 33 + t];
            ar[kx] = v.x; ai[kx] = v.y;
        }
        fft64<1>(ar, ai, cs, sn);
#pragma unroll
        for (int x = 0; x < 64; ++x) lds[x * 33 + t] = make_float2(ar[x], ai[x]);
    }
    __syncthreads();
}

__device__ __forceinline__ void ifft_pass_y(const float2* lds, float* xr,
                                            float* xi, const float* cs,
                                            const float* sn, int t) {
#pragma unroll
    for (int k = 0; k <= 32; ++k) {
        float2 v = lds[t * 33 + k];
        xr[k] = v.x; xi[k] = v.y;
    }
#pragma unroll
    for (int k = 33; k < 64; ++k) {
        float2 v = lds[t * 33 + (64 - k)];
        xr[k] = v.x; xi[k] = -v.y;
    }
    fft64<1>(xr, xi, cs, sn);
}

__device__ __forceinline__ void fwd_pass_y(float* xr, float* xi, float2* lds,
                                           const float* cs, const float* sn,
                                           int t) {
    fft64<-1>(xr, xi, cs, sn);
#pragma unroll
    for (int k = 0; k <= 32; ++k) lds[t * 33 + k] = make_float2(xr[k], xi[k]);
}

// forward fft along x of lds columns, results back into lds, then
// coalesced copy to global.
__device__ __forceinline__ void fwd_pass_x(float2* lds,
                                           float2* __restrict__ out,
                                           const float* cs, const float* sn,
                                           int t) {
    __syncthreads();
    if (t < 33) {
        float ar[64], ai[64];
#pragma unroll
        for (int x = 0; x < 64; ++x) {
            float2 v = lds[x * 33 + t];
            ar[x] = v.x; ai[x] = v.y;
        }
        fft64<-1>(ar, ai, cs, sn);
#pragma unroll
        for (int kx = 0; kx < 64; ++kx) lds[kx * 33 + t] = make_float2(ar[kx], ai[kx]);
    }
    __syncthreads();
    copy_l2g((float4*)out, (const float4*)lds, t);
}

// ---------------- h0 = x*Wi[c]+bi[c], then rfft2 -> Hf ---------------------
__global__ __launch_bounds__(64) void k_h0fft(const float* __restrict__ x,
                                              const float* __restrict__ Wi,
                                              const float* __restrict__ bi,
                                              float* __restrict__ h,
                                              float2* __restrict__ Hf) {
    __shared__ float cs[64], sn[64];
    __shared__ float4 lds4[1056];
    float2* lds = (float2*)lds4;
    const int t = threadIdx.x;
    init_twiddles(cs, sn, t);
    __syncthreads();
    const int ib = blockIdx.x;        // b*64+c
    const int c = ib & 63, b = ib >> 6;
    const float wi = Wi[c], bc = bi[c];

    float xr[64], xi[64];
    const float4* xrow = (const float4*)(x + (size_t)b * IMGSZ + t * 64);
    float4* hrow = (float4*)(h + (size_t)ib * IMGSZ + t * 64);
#pragma unroll
    for (int k = 0; k < 16; ++k) {
        float4 v = xrow[k];
        v.x = v.x * wi + bc; v.y = v.y * wi + bc;
        v.z = v.z * wi + bc; v.w = v.w * wi + bc;
        hrow[k] = v;
        xr[4 * k + 0] = v.x; xr[4 * k + 1] = v.y;
        xr[4 * k + 2] = v.z; xr[4 * k + 3] = v.w;
    }
#pragma unroll
    for (int k = 0; k < 64; ++k) xi[k] = 0.0f;
    fwd_pass_y(xr, xi, lds, cs, sn, t);
    fwd_pass_x(lds, Hf + (size_t)ib * NFREQ, cs, sn, t);
}

// ---------------- irfft2(Rf) -> r; rh = sigmoid(r)*h; rfft2(rh) -> RHf -----
__global__ __launch_bounds__(64) void k_fifft_r(const float2* __restrict__ Rf,
                                                const float* __restrict__ h,
                                                float2* __restrict__ RHf) {
    __shared__ float cs[64], sn[64];
    __shared__ float4 lds4[1056];
    float2* lds = (float2*)lds4;
    const int t = threadIdx.x;
    init_twiddles(cs, sn, t);
    const size_t ib = blockIdx.x;
    float xr[64], xi[64];

    ifft_pass_x(Rf + ib * NFREQ, lds, cs, sn, t);
    ifft_pass_y(lds, xr, xi, cs, sn, t);
    const float4* h4 = (const float4*)(h + ib * IMGSZ + t * 64);
#pragma unroll
    for (int k = 0; k < 16; ++k) {
        float4 hv = h4[k];
        xr[4 * k + 0] = sigmoidf_(xr[4 * k + 0] * INV_N) * hv.x;
        xr[4 * k + 1] = sigmoidf_(xr[4 * k + 1] * INV_N) * hv.y;
        xr[4 * k + 2] = sigmoidf_(xr[4 * k + 2] * INV_N) * hv.z;
        xr[4 * k + 3] = sigmoidf_(xr[4 * k + 3] * INV_N) * hv.w;
    }
#pragma unroll
    for (int k = 0; k < 64; ++k) xi[k] = 0.0f;
    fwd_pass_y(xr, xi, lds, cs, sn, t);
    fwd_pass_x(lds, RHf + ib * NFREQ, cs, sn, t);
}

// ---- irfft2(Zf)->z, irfft2(Nf)->n, h=(1-z)h+z*tanh(n); write h + rfft2(h) -
__global__ __launch_bounds__(64) void k_fifft_n(const float2* __restrict__ Nf,
                                                const float2* __restrict__ Zf,
                                                float* __restrict__ h,
                                                float2* __restrict__ Hfn) {
    __shared__ float cs[64], sn[64];
    __shared__ float4 lds4[1056];
    __shared__ float zbuf[64 * 65];   // padded: bank = (t+k)&31, conflict-free
    float2* lds = (float2*)lds4;
    const int t = threadIdx.x;
    init_twiddles(cs, sn, t);
    const size_t ib = blockIdx.x;
    float xr[64], xi[64];

    ifft_pass_x(Zf + ib * NFREQ, lds, cs, sn, t);
    ifft_pass_y(lds, xr, xi, cs, sn, t);
#pragma unroll
    for (int k = 0; k < 64; ++k) zbuf[t * 65 + k] = sigmoidf_(xr[k] * INV_N);

    ifft_pass_x(Nf + ib * NFREQ, lds, cs, sn, t);
    ifft_pass_y(lds, xr, xi, cs, sn, t);
    float4* h4 = (float4*)(h + ib * IMGSZ + t * 64);
    const float* zrow = zbuf + t * 65;
#pragma unroll
    for (int k = 0; k < 16; ++k) {
        float4 hv = h4[k];
        const float z0 = zrow[4 * k + 0], z1 = zrow[4 * k + 1];
        const float z2 = zrow[4 * k + 2], z3 = zrow[4 * k + 3];
        hv.x = (1.0f - z0) * hv.x + z0 * tanhf(xr[4 * k + 0] * INV_N);
        hv.y = (1.0f - z1) * hv.y + z1 * tanhf(xr[4 * k + 1] * INV_N);
        hv.z = (1.0f - z2) * hv.z + z2 * tanhf(xr[4 * k + 2] * INV_N);
        hv.w = (1.0f - z3) * hv.w + z3 * tanhf(xr[4 * k + 3] * INV_N);
        h4[k] = hv;
        xr[4 * k + 0] = hv.x; xr[4 * k + 1] = hv.y;
        xr[4 * k + 2] = hv.z; xr[4 * k + 3] = hv.w;
    }
#pragma unroll
    for (int k = 0; k < 64; ++k) xi[k] = 0.0f;
    fwd_pass_y(xr, xi, lds, cs, sn, t);
    fwd_pass_x(lds, Hfn + ib * NFREQ, cs, sn, t);
}

// ---------------- pointwise complex channel mix ----------------------------
// O[b][o][f] = sum_i H[b][i][f] * w[i][o][f]   (complex)
// grid (66, 8, 4): x = 32-complex-freq tile, y = 8-o group, z = 4-b group.
// 128 threads = 2 waves; thread t: fq = t&7 (4 cf), og = (t>>3)&7,
// w = t>>6 in {0,1}; wave w owns b-pair b0 = z*4 + w*2.
// T14 reg-staged double buffer, KI=2 per batch, prefetch distance 2
// (batch k: loaded iter k-3 via reg set (k&1), ds_written iter k-1 to
// LDS[k&1], consumed iter k). Staging assignment (re-derived for 2 waves):
//   pw2: wave w stages weight arrays 2w (zr/rr) and 2w+1 (zi/ri), both ki,
//        + Hf row i0+w -> 5 global loads + 5 ds_writes per wave per batch.
//   Wl[buf][ki][arr][o*8+fq] lane l writes [arr][l]; Hl[buf][ki][b_loc]
//   [slot] lane l writes linear l (b_loc = l>>4 in 0..3, slot = l&15).
__device__ __forceinline__ void cmadd4(float (&are)[4], float (&aim)[4],
                                       const float4 hA, const float4 hB,
                                       const float4 wr, const float4 wi) {
    are[0] += hA.x * wr.x - hA.y * wi.x;  aim[0] += hA.x * wi.x + hA.y * wr.x;
    are[1] += hA.z * wr.y - hA.w * wi.y;  aim[1] += hA.z * wi.y + hA.w * wr.y;
    are[2] += hB.x * wr.z - hB.y * wi.z;  aim[2] += hB.x * wi.z + hB.y * wr.z;
    are[3] += hB.z * wr.w - hB.w * wi.w;  aim[3] += hB.z * wi.w + hB.w * wr.w;
}

__global__ __launch_bounds__(128) void k_pw2(const float2* __restrict__ Hf,
                                             const float* __restrict__ wzr,
                                             const float* __restrict__ wzi,
                                             const float* __restrict__ wrr,
                                             const float* __restrict__ wri,
                                             float2* __restrict__ Zf,
                                             float2* __restrict__ Rf) {
    __shared__ float4 Wl[2][2][4][64];   // 16 KB
    __shared__ float4 Hl[2][2][4][16];   //  4 KB
    const int t  = threadIdx.x;
    const int l  = t & 63, w = t >> 6;       // lane, wave in {0,1}
    const int fq = t & 7,  og = (t >> 3) & 7;
    const int o  = blockIdx.y * 8 + og;
    const int b0 = blockIdx.z * 4 + w * 2;   // this wave's b-pair
    const int fA = blockIdx.x * 32 + fq * 4;
    const size_t wstep = (size_t)64 * NFREQ;

    // staging source bases: wave w stages arrays 2w (zr/rr), 2w+1 (zi/ri)
    const int o_l = l >> 3, fq_l = l & 7;
    const size_t woff = (size_t)(blockIdx.y * 8 + o_l) * NFREQ
                      + blockIdx.x * 32 + fq_l * 4;
    const float* ws0 = ((w == 0) ? wzr : wrr) + woff;
    const float* ws1 = ((w == 0) ? wzi : wri) + woff;
    // Hf: lane l covers b_loc = l>>4 (0..3), slot = l&15; wave w stages ki=w
    const float2* hsrc = Hf + (size_t)((blockIdx.z * 4 + (l >> 4)) * 64) * NFREQ
                            + blockIdx.x * 32 + (l & 15) * 2;

    float4 a00, a01, a10, a11, ah;   // reg set A (even batches)
    float4 b00, b01, b10, b11, bh;   // reg set B (odd batches)

#define LOADB(ii, r00, r01, r10, r11, rh_) do {                                \
        r00 = *(const float4*)(ws0 + (size_t)(2 * (ii)) * wstep);              \
        r01 = *(const float4*)(ws0 + (size_t)(2 * (ii) + 1) * wstep);          \
        r10 = *(const float4*)(ws1 + (size_t)(2 * (ii)) * wstep);              \
        r11 = *(const float4*)(ws1 + (size_t)(2 * (ii) + 1) * wstep);          \
        rh_ = *(const float4*)(hsrc + (size_t)(2 * (ii) + w) * NFREQ);         \
    } while (0)
#define WRITEB(bf, r00, r01, r10, r11, rh_) do {                               \
        Wl[bf][0][2 * w][l]     = r00;                                         \
        Wl[bf][1][2 * w][l]     = r01;                                         \
        Wl[bf][0][2 * w + 1][l] = r10;                                         \
        Wl[bf][1][2 * w + 1][l] = r11;                                         \
        (&Hl[bf][w][0][0])[l]   = rh_;                                         \
    } while (0)
#define COMP(bf) do {                                                          \
        _Pragma("unroll")                                                      \
        for (int ki = 0; ki < 2; ++ki) {                                       \
            const float4 vzr = Wl[bf][ki][0][og * 8 + fq];                     \
            const float4 vzi = Wl[bf][ki][1][og * 8 + fq];                     \
            const float4 vrr = Wl[bf][ki][2][og * 8 + fq];                     \
            const float4 vri = Wl[bf][ki][3][og * 8 + fq];                     \
            _Pragma("unroll")                                                  \
            for (int bb = 0; bb < 2; ++bb) {                                   \
                const float4 hA = Hl[bf][ki][w * 2 + bb][2 * fq];              \
                const float4 hB = Hl[bf][ki][w * 2 + bb][2 * fq + 1];          \
                cmadd4(zre[bb], zim[bb], hA, hB, vzr, vzi);                    \
                cmadd4(rre[bb], rim[bb], hA, hB, vrr, vri);                    \
            }                                                                  \
        }                                                                      \
    } while (0)

    float zre[2][4], zim[2][4], rre[2][4], rim[2][4];
#pragma unroll
    for (int b = 0; b < 2; ++b)
#pragma unroll
        for (int k = 0; k < 4; ++k) {
            zre[b][k] = 0.0f; zim[b][k] = 0.0f;
            rre[b][k] = 0.0f; rim[b][k] = 0.0f;
        }

    // prologue: batch0 -> LDS0 (via A); batch1 -> B; batch2 -> A (in flight)
    LOADB(0, a00, a01, a10, a11, ah);
    WRITEB(0, a00, a01, a10, a11, ah);
    LOADB(1, b00, b01, b10, b11, bh);
    LOADB(2, a00, a01, a10, a11, ah);
    __syncthreads();

    for (int s = 0; s < 32; s += 2) {
        // iter s (even): B holds batch s+1 -> LDS[1]; load batch s+3 -> B
        WRITEB(1, b00, b01, b10, b11, bh);
        if (s < 29) LOADB(s + 3, b00, b01, b10, b11, bh);
        COMP(0);
        __syncthreads();
        // iter s+1 (odd): A holds batch s+2 -> LDS[0]; load batch s+4 -> A
        if (s < 30) WRITEB(0, a00, a01, a10, a11, ah);
        if (s < 28) LOADB(s + 4, a00, a01, a10, a11, ah);
        COMP(1);
        __syncthreads();
    }
#undef LOADB
#undef WRITEB
#undef COMP

#pragma unroll
    for (int b = 0; b < 2; ++b) {
        float4* pz = (float4*)(Zf + (size_t)((b0 + b) * 64 + o) * NFREQ + fA);
        float4* pr = (float4*)(Rf + (size_t)((b0 + b) * 64 + o) * NFREQ + fA);
        pz[0] = make_float4(zre[b][0], zim[b][0], zre[b][1], zim[b][1]);
        pz[1] = make_float4(zre[b][2], zim[b][2], zre[b][3], zim[b][3]);
        pr[0] = make_float4(rre[b][0], rim[b][0], rre[b][1], rim[b][1]);
        pr[1] = make_float4(rre[b][2], rim[b][2], rre[b][3], rim[b][3]);
    }
}

// pw1: wave w stages whr+whi at ki=w and Hf ki=w -> 3 loads/wave/batch.
__global__ __launch_bounds__(128) void k_pw1(const float2* __restrict__ Hf,
                                             const float* __restrict__ whr,
                                             const float* __restrict__ whi,
                                             float2* __restrict__ Of) {
    __shared__ float4 Wl[2][2][2][64];   // 8 KB
    __shared__ float4 Hl[2][2][4][16];   // 4 KB
    const int t  = threadIdx.x;
    const int l  = t & 63, w = t >> 6;
    const int fq = t & 7,  og = (t >> 3) & 7;
    const int o  = blockIdx.y * 8 + og;
    const int b0 = blockIdx.z * 4 + w * 2;
    const int fA = blockIdx.x * 32 + fq * 4;
    const size_t wstep = (size_t)64 * NFREQ;

    const int o_l = l >> 3, fq_l = l & 7;
    const size_t woff = (size_t)(blockIdx.y * 8 + o_l) * NFREQ
                      + blockIdx.x * 32 + fq_l * 4;
    const float* wsr = whr + woff;
    const float* wsi = whi + woff;
    const float2* hsrc = Hf + (size_t)((blockIdx.z * 4 + (l >> 4)) * 64) * NFREQ
                            + blockIdx.x * 32 + (l & 15) * 2;

    float4 awr, awi, ah;   // reg set A (even batches)
    float4 bwr, bwi, bh;   // reg set B (odd batches)

#define LOADB(ii, rr_, ri_, rh_) do {                                          \
        rr_ = *(const float4*)(wsr + (size_t)(2 * (ii) + w) * wstep);          \
        ri_ = *(const float4*)(wsi + (size_t)(2 * (ii) + w) * wstep);          \
        rh_ = *(const float4*)(hsrc + (size_t)(2 * (ii) + w) * NFREQ);         \
    } while (0)
#define WRITEB(bf, rr_, ri_, rh_) do {                                         \
        Wl[bf][w][0][l] = rr_;                                                 \
        Wl[bf][w][1][l] = ri_;                                                 \
        (&Hl[bf][w][0][0])[l] = rh_;                                           \
    } while (0)
#define COMP(bf) do {                                                          \
        _Pragma("unroll")                                                      \
        for (int ki = 0; ki < 2; ++ki) {                                       \
            const float4 vr = Wl[bf][ki][0][og * 8 + fq];                      \
            const float4 vi = Wl[bf][ki][1][og * 8 + fq];                      \
            _Pragma("unroll")                                                  \
            for (int bb = 0; bb < 2; ++bb) {                                   \
                const float4 hA = Hl[bf][ki][w * 2 + bb][2 * fq];              \
                const float4 hB = Hl[bf][ki][w * 2 + bb][2 * fq + 1];          \
                cmadd4(cre[bb], cim[bb], hA, hB, vr, vi);                      \
            }                                                                  \
        }                                                                      \
    } while (0)

    float cre[2][4], cim[2][4];
#pragma unroll
    for (int b = 0; b < 2; ++b)
#pragma unroll
        for (int k = 0; k < 4; ++k) { cre[b][k] = 0.0f; cim[b][k] = 0.0f; }

    LOADB(0, awr, awi, ah);
    WRITEB(0, awr, awi, ah);
    LOADB(1, bwr, bwi, bh);
    LOADB(2, awr, awi, ah);
    __syncthreads();

    for (int s = 0; s < 32; s += 2) {
        WRITEB(1, bwr, bwi, bh);
        if (s < 29) LOADB(s + 3, bwr, bwi, bh);
        COMP(0);
        __syncthreads();
        if (s < 30) WRITEB(0, awr, awi, ah);
        if (s < 28) LOADB(s + 4, awr, awi, ah);
        COMP(1);
        __syncthreads();
    }
#undef LOADB
#undef WRITEB
#undef COMP

#pragma unroll
    for (int b = 0; b < 2; ++b) {
        float4* po = (float4*)(Of + (size_t)((b0 + b) * 64 + o) * NFREQ + fA);
        po[0] = make_float4(cre[b][0], cim[b][0], cre[b][1], cim[b][1]);
        po[1] = make_float4(cre[b][2], cim[b][2], cre[b][3], cim[b][3]);
    }
}

// ---------------- y = h @ Wo + bo, per step --------------------------------
__global__ __launch_bounds__(256) void k_yproj(const float* __restrict__ h,
                                               const float* __restrict__ Wo,
                                               const float* __restrict__ bo,
                                               float* __restrict__ out,
                                               int step) {
    __shared__ float wo[64];
    const int t = threadIdx.x;
    if (t < 64) wo[t] = Wo[t];
    __syncthreads();
    const int b = blockIdx.x >> 4, xg = blockIdx.x & 15;
    const int xx = xg * 4 + (t >> 6), y = t & 63;
    const float* hp = h + (size_t)b * 64 * IMGSZ + xx * 64 + y;
    float acc = bo[0];
#pragma unroll 8
    for (int c = 0; c < 64; ++c) acc += hp[(size_t)c * IMGSZ] * wo[c];
    out[((size_t)b * 20 + step) * IMGSZ + xx * 64 + y] = acc;
}

// ---------------------------------------------------------------------------
extern "C" void kernel_launch(void* const* d_in, const int* in_sizes, int n_in,
                              void* d_out, int out_size, void* d_ws, size_t ws_size,
                              hipStream_t stream) {
    const float* x    = (const float*)d_in[0];
    // d_in[1] = num_time_steps (always 20 per setup_inputs)
    const float* Wi   = (const float*)d_in[2];
    const float* bi   = (const float*)d_in[3];
    const float* Wo   = (const float*)d_in[4];
    const float* bo   = (const float*)d_in[5];
    const float* Wz_r = (const float*)d_in[6];
    const float* Wz_i = (const float*)d_in[7];
    const float* Wr_r = (const float*)d_in[8];
    const float* Wr_i = (const float*)d_in[9];
    const float* Wh_r = (const float*)d_in[10];
    const float* Wh_i = (const float*)d_in[11];

    float* ws = (float*)d_ws;
    float* h = ws;                              // 4,194,304 floats
    float2* B0 = (float2*)(ws + 4194304);       // 2,162,688 float2 each
    float2* B1 = B0 + 2162688;
    float2* B2 = B1 + 2162688;
    float* outp = (float*)d_out;

    k_h0fft<<<NIMG, 64, 0, stream>>>(x, Wi, bi, h, B0);   // h0, Hf -> B0

    for (int t = 0; t < 20; ++t) {
        k_pw2<<<dim3(66, 8, 4), 128, 0, stream>>>(B0, Wz_r, Wz_i, Wr_r, Wr_i,
                                                  B1, B2);  // Zf->B1 Rf->B2
        k_fifft_r<<<NIMG, 64, 0, stream>>>(B2, h, B2);      // RHf -> B2
        k_pw1<<<dim3(66, 8, 4), 128, 0, stream>>>(B2, Wh_r, Wh_i, B0); // Nf->B0
        k_fifft_n<<<NIMG, 64, 0, stream>>>(B0, B1, h, B0);  // h, Hf_next -> B0
        k_yproj<<<256, 256, 0, stream>>>(h, Wo, bo, outp, t);
    }
}